// Round 21
// baseline (744.805 us; speedup 1.0000x reference)
//
#include <hip/hip_runtime.h>

#define M_  4
#define B_  2
#define T_  1024
#define D_  512
#define V_  128
#define L_  4
#define H_  8
#define FF_ 2048
#define DK_ 64
#define BT_ (B_*T_)
#define EPS_ 1e-5f
#define QSCALE_ 0.18033688f   // 0.125 * log2(e): folded into Q at qkv epilogue

typedef __attribute__((ext_vector_type(8))) short  bf16x8;
typedef __attribute__((ext_vector_type(4))) float  f32x4;
typedef __attribute__((ext_vector_type(8))) ushort ushort8v;

__device__ __forceinline__ float b2f(ushort u) {
  union { unsigned int i; float f; } c; c.i = ((unsigned int)u) << 16; return c.f;
}
__device__ __forceinline__ ushort f2b(float f) {
  union { float f; unsigned int i; } c; c.f = f;
  return (ushort)((c.i + 0x7FFFu + ((c.i >> 16) & 1u)) >> 16);
}
__device__ __forceinline__ void gload_lds16(const void* g, void* l) {
  __builtin_amdgcn_global_load_lds((const __attribute__((address_space(1))) unsigned int*)g,
                                   (__attribute__((address_space(3))) unsigned int*)l, 16, 0, 0);
}

// ---------------- embedding: h (bf16) = tok + pos ----------------
__global__ __launch_bounds__(128)
void k_embed(const int* __restrict__ x, const float* __restrict__ tok,
             const float* __restrict__ pos, ushort* __restrict__ h)
{
  const int t = blockIdx.x, b = blockIdx.y, m = blockIdx.z;
  const int d = threadIdx.x * 4;
  const int xv = x[b*T_ + t];
  const float4 tv = *(const float4*)&tok[((size_t)m*V_ + xv)*D_ + d];
  const float4 pv = *(const float4*)&pos[((size_t)m*1024 + t)*D_ + d];
  ushort4 r;
  r.x = f2b(tv.x + pv.x); r.y = f2b(tv.y + pv.y);
  r.z = f2b(tv.z + pv.z); r.w = f2b(tv.w + pv.w);
  *(ushort4*)&h[(((size_t)m*B_ + b)*T_ + t)*D_ + d] = r;
}

// ---------------- layernorm: one WAVE per row; bf16 in, bf16 out ----------------
__global__ __launch_bounds__(256)
void k_ln(const ushort* __restrict__ x, const float* __restrict__ w,
          const float* __restrict__ bb, ushort* __restrict__ y)
{
  const int row  = blockIdx.x * 4 + (threadIdx.x >> 6);
  const int lane = threadIdx.x & 63;
  const int m = row >> 11;                 // row / BT_
  const ushort8v xv = *(const ushort8v*)&x[(size_t)row*D_ + lane*8];
  float v[8];
  #pragma unroll
  for (int k = 0; k < 8; ++k) v[k] = b2f(xv[k]);
  float s = 0.f, s2 = 0.f;
  #pragma unroll
  for (int k = 0; k < 8; ++k) { s += v[k]; s2 += v[k]*v[k]; }
  #pragma unroll
  for (int off = 1; off < 64; off <<= 1) {
    s  += __shfl_xor(s, off);
    s2 += __shfl_xor(s2, off);
  }
  const float mu   = s * (1.0f/D_);
  const float var  = s2 * (1.0f/D_) - mu*mu;
  const float rstd = rsqrtf(var + EPS_);
  const float* wp = w + m*D_ + lane*8;
  const float* bp = bb + m*D_ + lane*8;
  const float4 w0 = *(const float4*)wp, w1 = *(const float4*)(wp+4);
  const float4 b0 = *(const float4*)bp, b1 = *(const float4*)(bp+4);
  const float wr[8] = {w0.x,w0.y,w0.z,w0.w,w1.x,w1.y,w1.z,w1.w};
  const float br[8] = {b0.x,b0.y,b0.z,b0.w,b1.x,b1.y,b1.z,b1.w};
  ushort8v o;
  #pragma unroll
  for (int k = 0; k < 8; ++k) o[k] = f2b((v[k]-mu)*rstd*wr[k] + br[k]);
  *(ushort8v*)&y[(size_t)row*D_ + lane*8] = o;
}

// ---------------- MFMA GEMM: 128x128, BK=64, swizzled LDS ----------------
// A (activations): bf16, global_load_lds staged, dbuf + counted vmcnt.
// W (weights): fp32 in HBM, reg-staged (issue-early / write-late) with on-the-fly
//   RNE f2b conversion — eliminates the separate weight-cvt kernel entirely.
// Queue discipline (order pinned by sched_barrier between issue groups):
//   iter kt: issue B(kt+1)[8] ; issue A(kt+1)[4] ; vmcnt(12) retires A(kt) ;
//   lgkmcnt(0) [B(kt) ds_writes visible] ; B1 ; MFMA(kt) ; B2 ;
//   vmcnt(4) retires B(kt+1) regs ; ds_write B(kt+1).
template<int OUTBF, int ACT, int RES, int HEADOUT, int SPLITV>
__global__ __launch_bounds__(256)
void k_gemm(const ushort* __restrict__ A, const float* __restrict__ W,
            const float* __restrict__ bias, const ushort* __restrict__ resid,
            void* __restrict__ C, ushort* __restrict__ vt, int RR, int NN, int KK)
{
  const int m  = blockIdx.z;
  const int r0 = blockIdx.x * 128;
  const int c0 = blockIdx.y * 128;
  const ushort* Am = A + (size_t)m*RR*KK;
  const float*  Wm = W + (size_t)m*NN*KK;

  __shared__ ushort As[2][128*64];
  __shared__ ushort Bs[2][128*64];

  const int tid  = threadIdx.x;
  const int lane = tid & 63;
  const int wave = tid >> 6;
  const int wr = wave >> 1, wc = wave & 1;
  const int fr = lane & 15;
  const int fq = lane >> 4;

  f32x4 acc[4][4];
  #pragma unroll
  for (int i = 0; i < 4; ++i)
    #pragma unroll
    for (int j = 0; j < 4; ++j)
      acc[i][j] = (f32x4){0.f,0.f,0.f,0.f};

  float4 br[8];   // fp32 weight staging regs (4 chunks x 2 float4), static-indexed

  auto issueA = [&](int kt, int buf) {
    const int k0 = kt * 64;
    #pragma unroll
    for (int i = 0; i < 4; ++i) {
      const int c = i*256 + tid;
      const int row = c >> 3, ch = c & 7;
      const int sch = ch ^ (row & 7);
      gload_lds16(Am + (size_t)(r0+row)*KK + k0 + sch*8, (ushort*)As[buf] + (size_t)c*8);
    }
  };
  auto issueB = [&](int kt) {
    const int k0 = kt * 64;
    #pragma unroll
    for (int i = 0; i < 4; ++i) {
      const int c = i*256 + tid;
      const int row = c >> 3, ch = c & 7;
      const int sch = ch ^ (row & 7);
      const float* p = Wm + (size_t)(c0+row)*KK + k0 + sch*8;
      br[2*i]   = *(const float4*)p;
      br[2*i+1] = *(const float4*)(p + 4);
    }
  };
  auto writeB = [&](int buf) {
    #pragma unroll
    for (int i = 0; i < 4; ++i) {
      const int c = i*256 + tid;
      ushort8v t;
      t[0]=f2b(br[2*i].x);   t[1]=f2b(br[2*i].y);
      t[2]=f2b(br[2*i].z);   t[3]=f2b(br[2*i].w);
      t[4]=f2b(br[2*i+1].x); t[5]=f2b(br[2*i+1].y);
      t[6]=f2b(br[2*i+1].z); t[7]=f2b(br[2*i+1].w);
      *(ushort8v*)&Bs[buf][(size_t)c*8] = t;
    }
  };

  // prologue: B0 regs + A0 glds; retire B0 (leave A0 in flight); write B0 to LDS
  issueB(0);
  __builtin_amdgcn_sched_barrier(0);
  issueA(0, 0);
  asm volatile("s_waitcnt vmcnt(4)" ::: "memory");
  writeB(0);

  const int NK = KK >> 6;
  for (int kt = 0; kt < NK; ++kt) {
    const int cur = kt & 1;

    if (kt + 1 < NK) {
      issueB(kt + 1);
      __builtin_amdgcn_sched_barrier(0);
      issueA(kt + 1, cur ^ 1);
      asm volatile("s_waitcnt vmcnt(12)" ::: "memory");   // retire A(kt)
    } else {
      asm volatile("s_waitcnt vmcnt(0)" ::: "memory");
    }
    asm volatile("s_waitcnt lgkmcnt(0)" ::: "memory");    // B(kt) ds_writes drained
    __builtin_amdgcn_sched_barrier(0);
    __builtin_amdgcn_s_barrier();          // B1: As/Bs[cur] staged for all waves

    #pragma unroll
    for (int kk = 0; kk < 2; ++kk) {
      bf16x8 af[4], bfv[4];
      #pragma unroll
      for (int i = 0; i < 4; ++i) {
        const int rowA = wr*64 + i*16 + fr;
        af[i]  = *(const bf16x8*)&As[cur][rowA*64 + (((kk*4 + fq) ^ (rowA & 7))*8)];
        const int rowB = wc*64 + i*16 + fr;
        bfv[i] = *(const bf16x8*)&Bs[cur][rowB*64 + (((kk*4 + fq) ^ (rowB & 7))*8)];
      }
      #pragma unroll
      for (int i = 0; i < 4; ++i)
        #pragma unroll
        for (int j = 0; j < 4; ++j)
          acc[i][j] = __builtin_amdgcn_mfma_f32_16x16x32_bf16(af[i], bfv[j], acc[i][j], 0, 0, 0);
    }
    __builtin_amdgcn_s_barrier();          // B2: all reads of buf[cur] done

    if (kt + 1 < NK) {
      asm volatile("s_waitcnt vmcnt(4)" ::: "memory");    // retire B(kt+1) regs
      writeB(cur ^ 1);
    }
  }

  const int colb = c0 + wc*64 + fr;
  float bi[4];
  #pragma unroll
  for (int j = 0; j < 4; ++j) bi[j] = bias[(size_t)m*NN + colb + j*16];

  if (SPLITV) {
    // qkv epilogue: V cols -> vt[d][t]; Q cols (sub<64) pre-scaled by QSCALE_
    #pragma unroll
    for (int i = 0; i < 4; ++i) {
      const int row0 = r0 + wr*64 + i*16 + fq*4;
      const int mbg = (blockIdx.z)*B_ + (row0 >> 10);
      const int t0  = row0 & 1023;
      #pragma unroll
      for (int j = 0; j < 4; ++j) {
        const int col = colb + j*16;
        const int hh2 = col / 192;
        const int sub = col - hh2*192;
        float v0 = acc[i][j][0] + bi[j];
        float v1 = acc[i][j][1] + bi[j];
        float v2 = acc[i][j][2] + bi[j];
        float v3 = acc[i][j][3] + bi[j];
        if (sub >= 128) {
          ushort4 pk;
          pk.x = f2b(v0); pk.y = f2b(v1); pk.z = f2b(v2); pk.w = f2b(v3);
          *(ushort4*)&vt[(((size_t)mbg*8 + hh2)*64 + (sub-128))*1024 + t0] = pk;
        } else {
          if (sub < 64) { v0 *= QSCALE_; v1 *= QSCALE_; v2 *= QSCALE_; v3 *= QSCALE_; }
          ushort* cp = (ushort*)C + ((size_t)m*RR + row0)*NN + col;
          cp[0*NN] = f2b(v0); cp[1*NN] = f2b(v1); cp[2*NN] = f2b(v2); cp[3*NN] = f2b(v3);
        }
      }
    }
  } else {
    #pragma unroll
    for (int i = 0; i < 4; ++i) {
      #pragma unroll
      for (int r = 0; r < 4; ++r) {
        const int row = r0 + wr*64 + i*16 + fq*4 + r;
        #pragma unroll
        for (int j = 0; j < 4; ++j) {
          float val = acc[i][j][r] + bi[j];
          if (ACT) val = fmaxf(val, 0.0f);
          const int col = colb + j*16;
          size_t oidx;
          if (HEADOUT) {
            const int b = row >> 10, t = row & 1023;
            oidx = (((size_t)b*M_ + m)*T_ + t)*V_ + col;
          } else {
            oidx = ((size_t)m*RR + row)*NN + col;
          }
          float v2 = val;
          if (RES) v2 += b2f(resid[oidx]);
          if (OUTBF) ((ushort*)C)[oidx] = f2b(v2);
          else       ((float*)C)[oidx]  = v2;
        }
      }
    }
  }
}

// ---------------- MFMA flash attention: swapped-QK, log2 softmax (Q pre-scaled), ----
// ---------------- tree reductions, peeled diag, XCD-locality block layout ----------
__global__ __launch_bounds__(256)
void k_attn_mfma(const ushort* __restrict__ qkvb, const ushort* __restrict__ vt,
                 ushort* __restrict__ o)
{
  const int hh   = blockIdx.x;   // 0..7 (innermost -> fixes XCD per head)
  const int pair = blockIdx.y;   // 0..7
  const int mbg  = blockIdx.z;

  __shared__ ushort Qs[64*64];
  __shared__ ushort Ks[2][64*64];
  __shared__ ushort Vs[2][64*64];
  __shared__ ushort Ps[4][16*80];

  const int tid  = threadIdx.x;
  const int lane = tid & 63;
  const int wave = tid >> 6;
  const int fr = lane & 15;
  const int fq = lane >> 4;

  const ushort* qk_base = qkvb + (size_t)mbg*T_*(3*D_) + hh*(3*DK_);
  const ushort* vt_base = vt + ((size_t)(mbg*8 + hh)*64)*1024;

  #pragma unroll 1
  for (int pass = 0; pass < 2; ++pass) {
    const int qb = pass ? (15 - pair) : pair;

    #pragma unroll
    for (int i = 0; i < 2; ++i) {
      const int c = wave*128 + i*64 + lane;
      const int row = c >> 3, ch = c & 7;
      const int sch = (ch ^ (row & 7)) * 8;
      gload_lds16(qk_base + (size_t)(qb*64 + row)*(3*D_) + sch,
                  (ushort*)Qs + (size_t)(wave*128 + i*64)*8);
      gload_lds16(qk_base + (size_t)row*(3*D_) + DK_ + sch,
                  (ushort*)Ks[0] + (size_t)(wave*128 + i*64)*8);
      gload_lds16(vt_base + (size_t)row*1024 + sch,
                  (ushort*)Vs[0] + (size_t)(wave*128 + i*64)*8);
    }
    __syncthreads();

    bf16x8 aQ[2];
    #pragma unroll
    for (int kc = 0; kc < 2; ++kc) {
      const int qrow = wave*16 + fr;
      aQ[kc] = *(const bf16x8*)&Qs[qrow*64 + (((kc*4 + fq) ^ (qrow&7))*8)];
    }

    float m_q = -3.0e38f, l_q = 0.0f;
    f32x4 Of[4];
    #pragma unroll
    for (int j = 0; j < 4; ++j) Of[j] = (f32x4){0.f,0.f,0.f,0.f};

    const int qrow_abs0 = qb*64 + wave*16 + fq*4;

    auto tile = [&](int kb, bool DIAG, bool PRE) {
      const int cur = kb & 1;
      if (PRE) {
        #pragma unroll
        for (int i = 0; i < 2; ++i) {
          const int c = wave*128 + i*64 + lane;
          const int row = c >> 3, ch = c & 7;
          const int sch = (ch ^ (row & 7)) * 8;
          gload_lds16(qk_base + (size_t)((kb+1)*64 + row)*(3*D_) + DK_ + sch,
                      (ushort*)Ks[cur^1] + (size_t)(wave*128 + i*64)*8);
          gload_lds16(vt_base + (size_t)row*1024 + (kb+1)*64 + sch,
                      (ushort*)Vs[cur^1] + (size_t)(wave*128 + i*64)*8);
        }
        asm volatile("s_waitcnt vmcnt(4)" ::: "memory");
      } else {
        asm volatile("s_waitcnt vmcnt(0)" ::: "memory");
      }
      __builtin_amdgcn_sched_barrier(0);
      __builtin_amdgcn_s_barrier();        // B1: Ks/Vs[cur] staged

      f32x4 acc[4];
      #pragma unroll
      for (int j = 0; j < 4; ++j) acc[j] = (f32x4){0.f,0.f,0.f,0.f};
      __builtin_amdgcn_s_setprio(1);
      #pragma unroll
      for (int kc = 0; kc < 2; ++kc) {
        #pragma unroll
        for (int j = 0; j < 4; ++j) {
          const int krow = j*16 + fr;
          const bf16x8 bK = *(const bf16x8*)&Ks[cur][krow*64 + (((kc*4 + fq) ^ (krow&7))*8)];
          acc[j] = __builtin_amdgcn_mfma_f32_16x16x32_bf16(bK, aQ[kc], acc[j], 0, 0, 0);
        }
      }
      __builtin_amdgcn_s_setprio(0);

      float sv[16];
      #pragma unroll
      for (int j = 0; j < 4; ++j)
        #pragma unroll
        for (int r = 0; r < 4; ++r) {
          float v = acc[j][r];
          if (DIAG && (j*16 + fq*4 + r) > (wave*16 + fr)) v = -3.0e38f;
          sv[j*4+r] = v;
        }
      float a0 = fmaxf(fmaxf(sv[0],  sv[1]),  sv[2]);
      float a1 = fmaxf(fmaxf(sv[3],  sv[4]),  sv[5]);
      float a2 = fmaxf(fmaxf(sv[6],  sv[7]),  sv[8]);
      float a3 = fmaxf(fmaxf(sv[9],  sv[10]), sv[11]);
      float a4 = fmaxf(fmaxf(sv[12], sv[13]), sv[14]);
      float rm = fmaxf(fmaxf(fmaxf(a0, a1), fmaxf(a2, a3)), fmaxf(a4, sv[15]));
      rm = fmaxf(rm, __shfl_xor(rm, 16));
      rm = fmaxf(rm, __shfl_xor(rm, 32));
      if (!__all(rm - m_q <= 8.0f)) {
        const float mn = fmaxf(m_q, rm);
        const float sc = exp2f(m_q - mn);
        m_q = mn;
        l_q *= sc;
        float scr[4];
        #pragma unroll
        for (int r = 0; r < 4; ++r) scr[r] = __shfl(sc, fq*4 + r);
        #pragma unroll
        for (int j = 0; j < 4; ++j)
          #pragma unroll
          for (int r = 0; r < 4; ++r) Of[j][r] *= scr[r];
      }
      float p[16];
      #pragma unroll
      for (int i2 = 0; i2 < 16; ++i2) p[i2] = exp2f(sv[i2] - m_q);
      float s0 = (p[0]+p[1]) + (p[2]+p[3]);
      float s1 = (p[4]+p[5]) + (p[6]+p[7]);
      float s2 = (p[8]+p[9]) + (p[10]+p[11]);
      float s3 = (p[12]+p[13]) + (p[14]+p[15]);
      float rs = (s0+s1) + (s2+s3);
      rs += __shfl_xor(rs, 16);
      rs += __shfl_xor(rs, 32);
      l_q += rs;

      #pragma unroll
      for (int j = 0; j < 4; ++j) {
        unsigned int lo, hi;
        asm("v_cvt_pk_bf16_f32 %0, %1, %2" : "=v"(lo) : "v"(p[j*4+0]), "v"(p[j*4+1]));
        asm("v_cvt_pk_bf16_f32 %0, %1, %2" : "=v"(hi) : "v"(p[j*4+2]), "v"(p[j*4+3]));
        const int idx = (fr*80 + j*16 + fq*4) ^ ((fr>>2)<<4);
        *(unsigned int*)&Ps[wave][idx]     = lo;
        *(unsigned int*)&Ps[wave][idx + 2] = hi;
      }

      __builtin_amdgcn_s_setprio(1);
      #pragma unroll
      for (int kc = 0; kc < 2; ++kc) {
        const int pidx = fr*80 + kc*32 + fq*8;
        const bf16x8 pa = *(const bf16x8*)&Ps[wave][pidx ^ ((fr>>2)<<4)];
        #pragma unroll
        for (int j = 0; j < 4; ++j) {
          const int vrow = j*16 + fr;
          const bf16x8 bV = *(const bf16x8*)&Vs[cur][vrow*64 + (((kc*4 + fq) ^ (vrow&7))*8)];
          Of[j] = __builtin_amdgcn_mfma_f32_16x16x32_bf16(pa, bV, Of[j], 0, 0, 0);
        }
      }
      __builtin_amdgcn_s_setprio(0);
      __builtin_amdgcn_s_barrier();        // B2: all reads of buf[cur] done
    };

    for (int kb = 0; kb < qb; ++kb) tile(kb, false, true);   // mask-free main loop
    tile(qb, true, false);                                   // peeled diagonal tile

    const float linv = 1.0f / l_q;
    float inv[4];
    #pragma unroll
    for (int r = 0; r < 4; ++r) inv[r] = __shfl(linv, fq*4 + r);
    #pragma unroll
    for (int r = 0; r < 4; ++r) {
      ushort* op = o + ((size_t)mbg*T_ + (qrow_abs0 + r))*D_ + hh*DK_ + fr;
      #pragma unroll
      for (int j = 0; j < 4; ++j)
        op[j*16] = f2b(Of[j][r] * inv[r]);
    }
  }
}

extern "C" void kernel_launch(void* const* d_in, const int* in_sizes, int n_in,
                              void* d_out, int out_size, void* d_ws, size_t ws_size,
                              hipStream_t stream)
{
  const int*   x       = (const int*)  d_in[0];
  const float* tok_emb = (const float*)d_in[1];
  const float* pos_emb = (const float*)d_in[2];
  const float* ln1_w   = (const float*)d_in[3];
  const float* ln1_b   = (const float*)d_in[4];
  const float* qkv_w   = (const float*)d_in[5];
  const float* qkv_b   = (const float*)d_in[6];
  const float* out_w   = (const float*)d_in[7];
  const float* out_b   = (const float*)d_in[8];
  const float* ln2_w   = (const float*)d_in[9];
  const float* ln2_b   = (const float*)d_in[10];
  const float* ff1_w   = (const float*)d_in[11];
  const float* ff1_b   = (const float*)d_in[12];
  const float* ff2_w   = (const float*)d_in[13];
  const float* ff2_b   = (const float*)d_in[14];
  const float* lnf_w   = (const float*)d_in[15];
  const float* lnf_b   = (const float*)d_in[16];
  const float* head_w  = (const float*)d_in[17];
  const float* head_b  = (const float*)d_in[18];
  float* outp = (float*)d_out;

  const size_t HS = (size_t)M_*B_*T_*D_;            // 4,194,304
  ushort* h     = (ushort*)d_ws;                    // bf16 residual, 8.39 MB
  ushort* nb    = h + HS;                           // 8.39 MB
  ushort* qkvb  = nb + HS;                          // 12.58M ushorts
  ushort* ob    = qkvb + (size_t)M_*B_*T_*3*D_;     // 4.19M ushorts
  ushort* fb    = qkvb;                             // overlay
  ushort* vtb   = ob + HS;                          // 4.19M ushorts

  const int ROWS = M_*B_*T_;

  k_embed<<<dim3(T_, B_, M_), 128, 0, stream>>>(x, tok_emb, pos_emb, h);

  for (int l = 0; l < L_; ++l) {
    k_ln<<<ROWS/4, 256, 0, stream>>>(h, ln1_w + l*M_*D_, ln1_b + l*M_*D_, nb);

    k_gemm<1,0,0,0,1><<<dim3(BT_/128, (3*D_)/128, M_), 256, 0, stream>>>(
        nb, qkv_w + (size_t)l*M_*3*D_*D_, qkv_b + l*M_*3*D_, nullptr, qkvb, vtb, BT_, 3*D_, D_);

    k_attn_mfma<<<dim3(H_, T_/128, M_*B_), 256, 0, stream>>>(qkvb, vtb, ob);

    k_gemm<1,0,1,0,0><<<dim3(BT_/128, D_/128, M_), 256, 0, stream>>>(
        ob, out_w + (size_t)l*M_*D_*D_, out_b + l*M_*D_, h, h, nullptr, BT_, D_, D_);

    k_ln<<<ROWS/4, 256, 0, stream>>>(h, ln2_w + l*M_*D_, ln2_b + l*M_*D_, nb);

    k_gemm<1,1,0,0,0><<<dim3(BT_/128, FF_/128, M_), 256, 0, stream>>>(
        nb, ff1_w + (size_t)l*M_*FF_*D_, ff1_b + l*M_*FF_, nullptr, fb, nullptr, BT_, FF_, D_);

    k_gemm<1,0,1,0,0><<<dim3(BT_/128, D_/128, M_), 256, 0, stream>>>(
        fb, ff2_w + (size_t)l*M_*D_*FF_, ff2_b + l*M_*D_, h, h, nullptr, BT_, D_, FF_);
  }

  k_ln<<<ROWS/4, 256, 0, stream>>>(h, lnf_w, lnf_b, nb);
  k_gemm<0,0,0,1,0><<<dim3(BT_/128, V_/128, M_), 256, 0, stream>>>(
      nb, head_w, head_b, nullptr, outp, nullptr, BT_, V_, D_);
}

// Round 22
// 571.636 us; speedup vs baseline: 1.3029x; 1.3029x over previous
//
#include <hip/hip_runtime.h>

#define M_  4
#define B_  2
#define T_  1024
#define D_  512
#define V_  128
#define L_  4
#define H_  8
#define FF_ 2048
#define DK_ 64
#define BT_ (B_*T_)
#define EPS_ 1e-5f
#define QSCALE_ 0.18033688f   // 0.125 * log2(e): folded into Q at qkv epilogue

typedef __attribute__((ext_vector_type(8))) short  bf16x8;
typedef __attribute__((ext_vector_type(4))) float  f32x4;
typedef __attribute__((ext_vector_type(8))) ushort ushort8v;

__device__ __forceinline__ float b2f(ushort u) {
  union { unsigned int i; float f; } c; c.i = ((unsigned int)u) << 16; return c.f;
}
__device__ __forceinline__ ushort f2b(float f) {
  union { float f; unsigned int i; } c; c.f = f;
  return (ushort)((c.i + 0x7FFFu + ((c.i >> 16) & 1u)) >> 16);
}
__device__ __forceinline__ void gload_lds16(const void* g, void* l) {
  __builtin_amdgcn_global_load_lds((const __attribute__((address_space(1))) unsigned int*)g,
                                   (__attribute__((address_space(3))) unsigned int*)l, 16, 0, 0);
}

// ---------------- embedding: h (bf16) = tok + pos ----------------
__global__ __launch_bounds__(128)
void k_embed(const int* __restrict__ x, const float* __restrict__ tok,
             const float* __restrict__ pos, ushort* __restrict__ h)
{
  const int t = blockIdx.x, b = blockIdx.y, m = blockIdx.z;
  const int d = threadIdx.x * 4;
  const int xv = x[b*T_ + t];
  const float4 tv = *(const float4*)&tok[((size_t)m*V_ + xv)*D_ + d];
  const float4 pv = *(const float4*)&pos[((size_t)m*1024 + t)*D_ + d];
  ushort4 r;
  r.x = f2b(tv.x + pv.x); r.y = f2b(tv.y + pv.y);
  r.z = f2b(tv.z + pv.z); r.w = f2b(tv.w + pv.w);
  *(ushort4*)&h[(((size_t)m*B_ + b)*T_ + t)*D_ + d] = r;
}

// ---------------- per-layer weight convert: 4 elems/thread, unit-stride ----------------
#define NQ4_ 786432
#define NO4_ 262144
#define NF4_ 1048576
#define CVT4_BLK_ ((NQ4_ + NO4_ + 2*NF4_) / 256)   // 12288
__global__ __launch_bounds__(256)
void k_cvt4(const float* __restrict__ s0, const float* __restrict__ s1,
            const float* __restrict__ s2, const float* __restrict__ s3,
            ushort* __restrict__ d0, ushort* __restrict__ d1,
            ushort* __restrict__ d2, ushort* __restrict__ d3)
{
  int i = blockIdx.x * 256 + threadIdx.x;
  const float* s; ushort* d;
  if (i < NQ4_)                    { s = s0; d = d0; }
  else if (i < NQ4_+NO4_)          { s = s1; d = d1; i -= NQ4_; }
  else if (i < NQ4_+NO4_+NF4_)     { s = s2; d = d2; i -= NQ4_+NO4_; }
  else                             { s = s3; d = d3; i -= NQ4_+NO4_+NF4_; }
  const float4 a = ((const float4*)s)[i];
  ushort4 o;
  o.x = f2b(a.x); o.y = f2b(a.y); o.z = f2b(a.z); o.w = f2b(a.w);
  ((ushort4*)d)[i] = o;
}

__global__ __launch_bounds__(256)
void k_cvt(const float* __restrict__ src, ushort* __restrict__ dst, int n4)
{
  const int i = blockIdx.x * 256 + threadIdx.x;
  if (i >= n4) return;
  const float4 a = ((const float4*)src)[i];
  ushort4 o;
  o.x = f2b(a.x); o.y = f2b(a.y); o.z = f2b(a.z); o.w = f2b(a.w);
  ((ushort4*)dst)[i] = o;
}

// ---------------- layernorm: one WAVE per row; bf16 in, bf16 out ----------------
__global__ __launch_bounds__(256)
void k_ln(const ushort* __restrict__ x, const float* __restrict__ w,
          const float* __restrict__ bb, ushort* __restrict__ y)
{
  const int row  = blockIdx.x * 4 + (threadIdx.x >> 6);
  const int lane = threadIdx.x & 63;
  const int m = row >> 11;                 // row / BT_
  const ushort8v xv = *(const ushort8v*)&x[(size_t)row*D_ + lane*8];
  float v[8];
  #pragma unroll
  for (int k = 0; k < 8; ++k) v[k] = b2f(xv[k]);
  float s = 0.f, s2 = 0.f;
  #pragma unroll
  for (int k = 0; k < 8; ++k) { s += v[k]; s2 += v[k]*v[k]; }
  #pragma unroll
  for (int off = 1; off < 64; off <<= 1) {
    s  += __shfl_xor(s, off);
    s2 += __shfl_xor(s2, off);
  }
  const float mu   = s * (1.0f/D_);
  const float var  = s2 * (1.0f/D_) - mu*mu;
  const float rstd = rsqrtf(var + EPS_);
  const float* wp = w + m*D_ + lane*8;
  const float* bp = bb + m*D_ + lane*8;
  const float4 w0 = *(const float4*)wp, w1 = *(const float4*)(wp+4);
  const float4 b0 = *(const float4*)bp, b1 = *(const float4*)(bp+4);
  const float wr[8] = {w0.x,w0.y,w0.z,w0.w,w1.x,w1.y,w1.z,w1.w};
  const float br[8] = {b0.x,b0.y,b0.z,b0.w,b1.x,b1.y,b1.z,b1.w};
  ushort8v o;
  #pragma unroll
  for (int k = 0; k < 8; ++k) o[k] = f2b((v[k]-mu)*rstd*wr[k] + br[k]);
  *(ushort8v*)&y[(size_t)row*D_ + lane*8] = o;
}

// ---------------- MFMA GEMM: 128x128, BK=64, swizzled LDS, dbuf + counted vmcnt ----------------
// RES: bf16 residual read (h); OUTBF: bf16 output. SPLITV: Q cols pre-scaled by QSCALE_.
template<int OUTBF, int ACT, int RES, int HEADOUT, int SPLITV>
__global__ __launch_bounds__(256)
void k_gemm(const ushort* __restrict__ A, const ushort* __restrict__ W,
            const float* __restrict__ bias, const ushort* __restrict__ resid,
            void* __restrict__ C, ushort* __restrict__ vt, int RR, int NN, int KK)
{
  const int m  = blockIdx.z;
  const int r0 = blockIdx.x * 128;
  const int c0 = blockIdx.y * 128;
  const ushort* Am = A + (size_t)m*RR*KK;
  const ushort* Wm = W + (size_t)m*NN*KK;

  __shared__ ushort As[2][128*64];
  __shared__ ushort Bs[2][128*64];

  const int tid  = threadIdx.x;
  const int lane = tid & 63;
  const int wave = tid >> 6;
  const int wr = wave >> 1, wc = wave & 1;
  const int fr = lane & 15;
  const int fq = lane >> 4;

  f32x4 acc[4][4];
  #pragma unroll
  for (int i = 0; i < 4; ++i)
    #pragma unroll
    for (int j = 0; j < 4; ++j)
      acc[i][j] = (f32x4){0.f,0.f,0.f,0.f};

  #pragma unroll
  for (int i = 0; i < 4; ++i) {
    const int c = i*256 + tid;
    const int row = c >> 3, ch = c & 7;
    const int sch = ch ^ (row & 7);
    gload_lds16(Am + (size_t)(r0+row)*KK + sch*8, (ushort*)As[0] + (size_t)c*8);
    gload_lds16(Wm + (size_t)(c0+row)*KK + sch*8, (ushort*)Bs[0] + (size_t)c*8);
  }
  __syncthreads();

  const int NK = KK >> 6;
  for (int kt = 0; kt < NK; ++kt) {
    const int cur = kt & 1;

    if (kt + 1 < NK) {
      const int k0 = (kt + 1) * 64;
      #pragma unroll
      for (int i = 0; i < 4; ++i) {
        const int c = i*256 + tid;
        const int row = c >> 3, ch = c & 7;
        const int sch = ch ^ (row & 7);
        gload_lds16(Am + (size_t)(r0+row)*KK + k0 + sch*8, (ushort*)As[cur^1] + (size_t)c*8);
        gload_lds16(Wm + (size_t)(c0+row)*KK + k0 + sch*8, (ushort*)Bs[cur^1] + (size_t)c*8);
      }
      asm volatile("s_waitcnt vmcnt(8)" ::: "memory");
    } else {
      asm volatile("s_waitcnt vmcnt(0)" ::: "memory");
    }
    __builtin_amdgcn_sched_barrier(0);
    __builtin_amdgcn_s_barrier();          // B1: buf[cur] fully staged for all waves

    #pragma unroll
    for (int kk = 0; kk < 2; ++kk) {
      bf16x8 af[4], bfv[4];
      #pragma unroll
      for (int i = 0; i < 4; ++i) {
        const int rowA = wr*64 + i*16 + fr;
        af[i]  = *(const bf16x8*)&As[cur][rowA*64 + (((kk*4 + fq) ^ (rowA & 7))*8)];
        const int rowB = wc*64 + i*16 + fr;
        bfv[i] = *(const bf16x8*)&Bs[cur][rowB*64 + (((kk*4 + fq) ^ (rowB & 7))*8)];
      }
      #pragma unroll
      for (int i = 0; i < 4; ++i)
        #pragma unroll
        for (int j = 0; j < 4; ++j)
          acc[i][j] = __builtin_amdgcn_mfma_f32_16x16x32_bf16(af[i], bfv[j], acc[i][j], 0, 0, 0);
    }
    __builtin_amdgcn_s_barrier();          // B2: all reads of buf[cur] done
  }

  const int colb = c0 + wc*64 + fr;
  float bi[4];
  #pragma unroll
  for (int j = 0; j < 4; ++j) bi[j] = bias[(size_t)m*NN + colb + j*16];

  if (SPLITV) {
    // qkv epilogue: V cols -> vt[d][t]; Q cols (sub<64) pre-scaled by QSCALE_
    #pragma unroll
    for (int i = 0; i < 4; ++i) {
      const int row0 = r0 + wr*64 + i*16 + fq*4;
      const int mbg = (blockIdx.z)*B_ + (row0 >> 10);
      const int t0  = row0 & 1023;
      #pragma unroll
      for (int j = 0; j < 4; ++j) {
        const int col = colb + j*16;
        const int hh2 = col / 192;
        const int sub = col - hh2*192;
        float v0 = acc[i][j][0] + bi[j];
        float v1 = acc[i][j][1] + bi[j];
        float v2 = acc[i][j][2] + bi[j];
        float v3 = acc[i][j][3] + bi[j];
        if (sub >= 128) {
          ushort4 pk;
          pk.x = f2b(v0); pk.y = f2b(v1); pk.z = f2b(v2); pk.w = f2b(v3);
          *(ushort4*)&vt[(((size_t)mbg*8 + hh2)*64 + (sub-128))*1024 + t0] = pk;
        } else {
          if (sub < 64) { v0 *= QSCALE_; v1 *= QSCALE_; v2 *= QSCALE_; v3 *= QSCALE_; }
          ushort* cp = (ushort*)C + ((size_t)m*RR + row0)*NN + col;
          cp[0*NN] = f2b(v0); cp[1*NN] = f2b(v1); cp[2*NN] = f2b(v2); cp[3*NN] = f2b(v3);
        }
      }
    }
  } else {
    #pragma unroll
    for (int i = 0; i < 4; ++i) {
      #pragma unroll
      for (int r = 0; r < 4; ++r) {
        const int row = r0 + wr*64 + i*16 + fq*4 + r;
        #pragma unroll
        for (int j = 0; j < 4; ++j) {
          float val = acc[i][j][r] + bi[j];
          if (ACT) val = fmaxf(val, 0.0f);
          const int col = colb + j*16;
          size_t oidx;
          if (HEADOUT) {
            const int b = row >> 10, t = row & 1023;
            oidx = (((size_t)b*M_ + m)*T_ + t)*V_ + col;
          } else {
            oidx = ((size_t)m*RR + row)*NN + col;
          }
          float v2 = val;
          if (RES) v2 += b2f(resid[oidx]);
          if (OUTBF) ((ushort*)C)[oidx] = f2b(v2);
          else       ((float*)C)[oidx]  = v2;
        }
      }
    }
  }
}

// ---------------- MFMA flash attention: swapped-QK, log2 softmax (Q pre-scaled), ----
// ---------------- tree reductions, peeled diag, XCD-locality block layout ----------
__global__ __launch_bounds__(256)
void k_attn_mfma(const ushort* __restrict__ qkvb, const ushort* __restrict__ vt,
                 ushort* __restrict__ o)
{
  const int hh   = blockIdx.x;   // 0..7 (innermost -> fixes XCD per head)
  const int pair = blockIdx.y;   // 0..7
  const int mbg  = blockIdx.z;

  __shared__ ushort Qs[64*64];
  __shared__ ushort Ks[2][64*64];
  __shared__ ushort Vs[2][64*64];
  __shared__ ushort Ps[4][16*80];

  const int tid  = threadIdx.x;
  const int lane = tid & 63;
  const int wave = tid >> 6;
  const int fr = lane & 15;
  const int fq = lane >> 4;

  const ushort* qk_base = qkvb + (size_t)mbg*T_*(3*D_) + hh*(3*DK_);
  const ushort* vt_base = vt + ((size_t)(mbg*8 + hh)*64)*1024;

  #pragma unroll 1
  for (int pass = 0; pass < 2; ++pass) {
    const int qb = pass ? (15 - pair) : pair;

    #pragma unroll
    for (int i = 0; i < 2; ++i) {
      const int c = wave*128 + i*64 + lane;
      const int row = c >> 3, ch = c & 7;
      const int sch = (ch ^ (row & 7)) * 8;
      gload_lds16(qk_base + (size_t)(qb*64 + row)*(3*D_) + sch,
                  (ushort*)Qs + (size_t)(wave*128 + i*64)*8);
      gload_lds16(qk_base + (size_t)row*(3*D_) + DK_ + sch,
                  (ushort*)Ks[0] + (size_t)(wave*128 + i*64)*8);
      gload_lds16(vt_base + (size_t)row*1024 + sch,
                  (ushort*)Vs[0] + (size_t)(wave*128 + i*64)*8);
    }
    __syncthreads();

    bf16x8 aQ[2];
    #pragma unroll
    for (int kc = 0; kc < 2; ++kc) {
      const int qrow = wave*16 + fr;
      aQ[kc] = *(const bf16x8*)&Qs[qrow*64 + (((kc*4 + fq) ^ (qrow&7))*8)];
    }

    float m_q = -3.0e38f, l_q = 0.0f;
    f32x4 Of[4];
    #pragma unroll
    for (int j = 0; j < 4; ++j) Of[j] = (f32x4){0.f,0.f,0.f,0.f};

    const int qrow_abs0 = qb*64 + wave*16 + fq*4;

    auto tile = [&](int kb, bool DIAG, bool PRE) {
      const int cur = kb & 1;
      if (PRE) {
        #pragma unroll
        for (int i = 0; i < 2; ++i) {
          const int c = wave*128 + i*64 + lane;
          const int row = c >> 3, ch = c & 7;
          const int sch = (ch ^ (row & 7)) * 8;
          gload_lds16(qk_base + (size_t)((kb+1)*64 + row)*(3*D_) + DK_ + sch,
                      (ushort*)Ks[cur^1] + (size_t)(wave*128 + i*64)*8);
          gload_lds16(vt_base + (size_t)row*1024 + (kb+1)*64 + sch,
                      (ushort*)Vs[cur^1] + (size_t)(wave*128 + i*64)*8);
        }
        asm volatile("s_waitcnt vmcnt(4)" ::: "memory");
      } else {
        asm volatile("s_waitcnt vmcnt(0)" ::: "memory");
      }
      __builtin_amdgcn_sched_barrier(0);
      __builtin_amdgcn_s_barrier();        // B1: Ks/Vs[cur] staged

      f32x4 acc[4];
      #pragma unroll
      for (int j = 0; j < 4; ++j) acc[j] = (f32x4){0.f,0.f,0.f,0.f};
      __builtin_amdgcn_s_setprio(1);
      #pragma unroll
      for (int kc = 0; kc < 2; ++kc) {
        #pragma unroll
        for (int j = 0; j < 4; ++j) {
          const int krow = j*16 + fr;
          const bf16x8 bK = *(const bf16x8*)&Ks[cur][krow*64 + (((kc*4 + fq) ^ (krow&7))*8)];
          acc[j] = __builtin_amdgcn_mfma_f32_16x16x32_bf16(bK, aQ[kc], acc[j], 0, 0, 0);
        }
      }
      __builtin_amdgcn_s_setprio(0);

      float sv[16];
      #pragma unroll
      for (int j = 0; j < 4; ++j)
        #pragma unroll
        for (int r = 0; r < 4; ++r) {
          float v = acc[j][r];
          if (DIAG && (j*16 + fq*4 + r) > (wave*16 + fr)) v = -3.0e38f;
          sv[j*4+r] = v;
        }
      float a0 = fmaxf(fmaxf(sv[0],  sv[1]),  sv[2]);
      float a1 = fmaxf(fmaxf(sv[3],  sv[4]),  sv[5]);
      float a2 = fmaxf(fmaxf(sv[6],  sv[7]),  sv[8]);
      float a3 = fmaxf(fmaxf(sv[9],  sv[10]), sv[11]);
      float a4 = fmaxf(fmaxf(sv[12], sv[13]), sv[14]);
      float rm = fmaxf(fmaxf(fmaxf(a0, a1), fmaxf(a2, a3)), fmaxf(a4, sv[15]));
      rm = fmaxf(rm, __shfl_xor(rm, 16));
      rm = fmaxf(rm, __shfl_xor(rm, 32));
      if (!__all(rm - m_q <= 8.0f)) {
        const float mn = fmaxf(m_q, rm);
        const float sc = exp2f(m_q - mn);
        m_q = mn;
        l_q *= sc;
        float scr[4];
        #pragma unroll
        for (int r = 0; r < 4; ++r) scr[r] = __shfl(sc, fq*4 + r);
        #pragma unroll
        for (int j = 0; j < 4; ++j)
          #pragma unroll
          for (int r = 0; r < 4; ++r) Of[j][r] *= scr[r];
      }
      float p[16];
      #pragma unroll
      for (int i2 = 0; i2 < 16; ++i2) p[i2] = exp2f(sv[i2] - m_q);
      float s0 = (p[0]+p[1]) + (p[2]+p[3]);
      float s1 = (p[4]+p[5]) + (p[6]+p[7]);
      float s2 = (p[8]+p[9]) + (p[10]+p[11]);
      float s3 = (p[12]+p[13]) + (p[14]+p[15]);
      float rs = (s0+s1) + (s2+s3);
      rs += __shfl_xor(rs, 16);
      rs += __shfl_xor(rs, 32);
      l_q += rs;

      #pragma unroll
      for (int j = 0; j < 4; ++j) {
        unsigned int lo, hi;
        asm("v_cvt_pk_bf16_f32 %0, %1, %2" : "=v"(lo) : "v"(p[j*4+0]), "v"(p[j*4+1]));
        asm("v_cvt_pk_bf16_f32 %0, %1, %2" : "=v"(hi) : "v"(p[j*4+2]), "v"(p[j*4+3]));
        const int idx = (fr*80 + j*16 + fq*4) ^ ((fr>>2)<<4);
        *(unsigned int*)&Ps[wave][idx]     = lo;
        *(unsigned int*)&Ps[wave][idx + 2] = hi;
      }

      __builtin_amdgcn_s_setprio(1);
      #pragma unroll
      for (int kc = 0; kc < 2; ++kc) {
        const int pidx = fr*80 + kc*32 + fq*8;
        const bf16x8 pa = *(const bf16x8*)&Ps[wave][pidx ^ ((fr>>2)<<4)];
        #pragma unroll
        for (int j = 0; j < 4; ++j) {
          const int vrow = j*16 + fr;
          const bf16x8 bV = *(const bf16x8*)&Vs[cur][vrow*64 + (((kc*4 + fq) ^ (vrow&7))*8)];
          Of[j] = __builtin_amdgcn_mfma_f32_16x16x32_bf16(pa, bV, Of[j], 0, 0, 0);
        }
      }
      __builtin_amdgcn_s_setprio(0);
      __builtin_amdgcn_s_barrier();        // B2: all reads of buf[cur] done
    };

    for (int kb = 0; kb < qb; ++kb) tile(kb, false, true);   // mask-free main loop
    tile(qb, true, false);                                   // peeled diagonal tile

    const float linv = 1.0f / l_q;
    float inv[4];
    #pragma unroll
    for (int r = 0; r < 4; ++r) inv[r] = __shfl(linv, fq*4 + r);
    #pragma unroll
    for (int r = 0; r < 4; ++r) {
      ushort* op = o + ((size_t)mbg*T_ + (qrow_abs0 + r))*D_ + hh*DK_ + fr;
      #pragma unroll
      for (int j = 0; j < 4; ++j)
        op[j*16] = f2b(Of[j][r] * inv[r]);
    }
  }
}

extern "C" void kernel_launch(void* const* d_in, const int* in_sizes, int n_in,
                              void* d_out, int out_size, void* d_ws, size_t ws_size,
                              hipStream_t stream)
{
  const int*   x       = (const int*)  d_in[0];
  const float* tok_emb = (const float*)d_in[1];
  const float* pos_emb = (const float*)d_in[2];
  const float* ln1_w   = (const float*)d_in[3];
  const float* ln1_b   = (const float*)d_in[4];
  const float* qkv_w   = (const float*)d_in[5];
  const float* qkv_b   = (const float*)d_in[6];
  const float* out_w   = (const float*)d_in[7];
  const float* out_b   = (const float*)d_in[8];
  const float* ln2_w   = (const float*)d_in[9];
  const float* ln2_b   = (const float*)d_in[10];
  const float* ff1_w   = (const float*)d_in[11];
  const float* ff1_b   = (const float*)d_in[12];
  const float* ff2_w   = (const float*)d_in[13];
  const float* ff2_b   = (const float*)d_in[14];
  const float* lnf_w   = (const float*)d_in[15];
  const float* lnf_b   = (const float*)d_in[16];
  const float* head_w  = (const float*)d_in[17];
  const float* head_b  = (const float*)d_in[18];
  float* outp = (float*)d_out;

  const size_t HS = (size_t)M_*B_*T_*D_;            // 4,194,304
  ushort* h     = (ushort*)d_ws;                    // bf16 residual, 8.39 MB
  ushort* nb    = h + HS;                           // 8.39 MB
  ushort* qkvb  = nb + HS;                          // 12.58M ushorts
  ushort* ob    = qkvb + (size_t)M_*B_*T_*3*D_;     // 4.19M ushorts
  ushort* fb    = qkvb;                             // overlay
  ushort* vtb   = ob + HS;                          // 4.19M ushorts
  ushort* wq    = vtb + HS;                         // weight slots (25.2 MB total)
  ushort* wo    = wq  + (size_t)M_*3*D_*D_;
  ushort* wf1   = wo  + (size_t)M_*D_*D_;
  ushort* wf2   = wf1 + (size_t)M_*FF_*D_;

  const int ROWS = M_*B_*T_;
  const int NH4 = M_*V_*D_/4;                       // 65536 -> 256 blocks

  k_embed<<<dim3(T_, B_, M_), 128, 0, stream>>>(x, tok_emb, pos_emb, h);

  for (int l = 0; l < L_; ++l) {
    k_cvt4<<<CVT4_BLK_, 256, 0, stream>>>(
        qkv_w + (size_t)l*M_*3*D_*D_, out_w + (size_t)l*M_*D_*D_,
        ff1_w + (size_t)l*M_*FF_*D_,  ff2_w + (size_t)l*M_*D_*FF_,
        wq, wo, wf1, wf2);

    k_ln<<<ROWS/4, 256, 0, stream>>>(h, ln1_w + l*M_*D_, ln1_b + l*M_*D_, nb);

    k_gemm<1,0,0,0,1><<<dim3(BT_/128, (3*D_)/128, M_), 256, 0, stream>>>(
        nb, wq, qkv_b + l*M_*3*D_, nullptr, qkvb, vtb, BT_, 3*D_, D_);

    k_attn_mfma<<<dim3(H_, T_/128, M_*B_), 256, 0, stream>>>(qkvb, vtb, ob);

    k_gemm<1,0,1,0,0><<<dim3(BT_/128, D_/128, M_), 256, 0, stream>>>(
        ob, wo, out_b + l*M_*D_, h, h, nullptr, BT_, D_, D_);

    k_ln<<<ROWS/4, 256, 0, stream>>>(h, ln2_w + l*M_*D_, ln2_b + l*M_*D_, nb);

    k_gemm<1,1,0,0,0><<<dim3(BT_/128, FF_/128, M_), 256, 0, stream>>>(
        nb, wf1, ff1_b + l*M_*FF_, nullptr, fb, nullptr, BT_, FF_, D_);

    k_gemm<1,0,1,0,0><<<dim3(BT_/128, D_/128, M_), 256, 0, stream>>>(
        fb, wf2, ff2_b + l*M_*D_, h, h, nullptr, BT_, D_, FF_);
  }

  k_ln<<<ROWS/4, 256, 0, stream>>>(h, lnf_w, lnf_b, nb);
  k_cvt<<<NH4/256, 256, 0, stream>>>(head_w, wq, NH4);
  k_gemm<0,0,0,1,0><<<dim3(BT_/128, V_/128, M_), 256, 0, stream>>>(
      nb, wq, head_b, nullptr, outp, nullptr, BT_, V_, D_);
}